// Round 5
// baseline (537.810 us; speedup 1.0000x reference)
//
#include <hip/hip_runtime.h>
#include <cstdint>
#include <cstddef>

#define NN 100000   // nodes
#define NE 1600000  // edges
#define DD 128      // feature dim
#define NG 64       // graphs
#define NB 782      // buckets of 128 nodes: 782*128 = 100096 >= NN

using bf16x8 = __attribute__((ext_vector_type(8))) short;
using f32x4  = __attribute__((ext_vector_type(4))) float;

__device__ __forceinline__ int clampi(int v, int hi) {
    v = v < 0 ? 0 : v;
    return v >= hi ? hi - 1 : v;
}
__device__ __forceinline__ unsigned short f2bf(float f) {
    unsigned int u = __float_as_uint(f);
    u += 0x7fffu + ((u >> 16) & 1u);   // RNE
    return (unsigned short)(u >> 16);
}
__device__ __forceinline__ float bf2f(unsigned short s) {
    return __uint_as_float(((unsigned int)s) << 16);
}

// ---------------------------------------------------------------------------
// CSR build via bucket sort (all dense writes — no line-amplified scatter)
// ---------------------------------------------------------------------------
__global__ __launch_bounds__(256) void bcount_kernel(
    const int* __restrict__ dst, int* __restrict__ bcnt) {
    __shared__ int lcnt[NB];
    for (int i = threadIdx.x; i < NB; i += 256) lcnt[i] = 0;
    __syncthreads();
    int e0 = blockIdx.x * 8000;
    int e1 = e0 + 8000; if (e1 > NE) e1 = NE;
    for (int e = e0 + threadIdx.x; e < e1; e += 256)
        atomicAdd(&lcnt[clampi(dst[e], NN) >> 7], 1);
    __syncthreads();
    for (int i = threadIdx.x; i < NB; i += 256)
        if (lcnt[i]) atomicAdd(&bcnt[i], lcnt[i]);
}

__global__ __launch_bounds__(1024) void bscan_kernel(
    const int* __restrict__ bcnt, int* __restrict__ bstart, int* __restrict__ gcur) {
    __shared__ int sh[1024];
    int t = threadIdx.x;
    int own = (t < NB) ? bcnt[t] : 0;
    sh[t] = own;
    __syncthreads();
    for (int d = 1; d < 1024; d <<= 1) {
        int v = (t >= d) ? sh[t - d] : 0;
        __syncthreads();
        sh[t] += v;
        __syncthreads();
    }
    if (t < NB) {
        int excl = sh[t] - own;
        bstart[t] = excl;
        gcur[t] = excl;
    }
    if (t == NB - 1) bstart[NB] = sh[t];
}

__global__ __launch_bounds__(256) void bpart_kernel(
    const int* __restrict__ src, const int* __restrict__ dst,
    int* __restrict__ gcur, uint2* __restrict__ stage) {
    __shared__ int lds[NB];
    for (int i = threadIdx.x; i < NB; i += 256) lds[i] = 0;
    __syncthreads();
    int e0 = blockIdx.x * 8000;
    int e1 = e0 + 8000; if (e1 > NE) e1 = NE;
    for (int e = e0 + threadIdx.x; e < e1; e += 256)
        atomicAdd(&lds[clampi(dst[e], NN) >> 7], 1);
    __syncthreads();
    for (int i = threadIdx.x; i < NB; i += 256) {
        int c = lds[i];
        if (c) lds[i] = atomicAdd(&gcur[i], c);
    }
    __syncthreads();
    for (int e = e0 + threadIdx.x; e < e1; e += 256) {
        int d = clampi(dst[e], NN);
        int pos = atomicAdd(&lds[d >> 7], 1);
        uint2 p; p.x = (unsigned)clampi(src[e], NN); p.y = (unsigned)d;
        stage[pos] = p;
    }
}

__global__ __launch_bounds__(256) void bfill_kernel(
    const uint2* __restrict__ stage, const int* __restrict__ bstart,
    int* __restrict__ row_ptr, int* __restrict__ csr) {
    __shared__ int scnt[128];
    __shared__ int scur[128];
    const int b = blockIdx.x;
    const int t = threadIdx.x;
    const int s0 = bstart[b], s1 = bstart[b + 1];
    const int n0 = b << 7;
    int nend = NN - n0; if (nend > 128) nend = 128;
    if (t < 128) scnt[t] = 0;
    __syncthreads();
    for (int i = s0 + t; i < s1; i += 256)
        atomicAdd(&scnt[stage[i].y & 127], 1);
    __syncthreads();
    int own = (t < 128) ? scnt[t] : 0;
    for (int d = 1; d < 128; d <<= 1) {
        int v = (t < 128 && t >= d) ? scnt[t - d] : 0;
        __syncthreads();
        if (t < 128) scnt[t] += v;
        __syncthreads();
    }
    if (t < 128) {
        int excl = scnt[t] - own;
        scur[t] = excl;
        if (t < nend) row_ptr[n0 + t] = s0 + excl;
    }
    if (b == NB - 1 && t == 0) row_ptr[NN] = NE;
    __syncthreads();
    for (int i = s0 + t; i < s1; i += 256) {
        uint2 p = stage[i];
        int slot = atomicAdd(&scur[p.y & 127], 1);
        csr[s0 + slot] = (int)p.x;
    }
}

// ---------------------------------------------------------------------------
// Convert kernels
// ---------------------------------------------------------------------------
__global__ void cvt_x_kernel(const float* __restrict__ x, unsigned short* __restrict__ xb) {
    int i = blockIdx.x * 256 + threadIdx.x;
    if (i >= NN * DD / 4) return;
    const float4 v = ((const float4*)x)[i];
    ushort4 r;
    r.x = f2bf(v.x); r.y = f2bf(v.y); r.z = f2bf(v.z); r.w = f2bf(v.w);
    ((ushort4*)xb)[i] = r;
}

__global__ void cvt_w_kernel(const float* __restrict__ Wl, const float* __restrict__ Wr,
                             unsigned short* __restrict__ Wcat) {
    int t = blockIdx.x * 256 + threadIdx.x;
    if (t >= 3 * 128 * 256) return;
    int l = t >> 15;
    int rem = t & 32767;
    int o = rem >> 8, k = rem & 255;
    float v = (k < 128) ? Wl[(size_t)l * 16384 + o * 128 + k]
                        : Wr[(size_t)l * 16384 + o * 128 + (k - 128)];
    Wcat[t] = f2bf(v);
}

// ---------------------------------------------------------------------------
// Fused SAGE layer: gather(mean of neighbors) -> LDS, then MFMA
// out = relu(normalize(h@Wl^T + agg@Wr^T + bl + [deg>0]*br)) -> bf16
// Block: 256 thr = 4 waves, 64 dst nodes. LDS agg tile [64][136] bf16 (padded).
// Gather: wave w owns nodes [16w,16w+16); 4 lane-groups of 16, 4-deep unroll.
// ---------------------------------------------------------------------------
__global__ __launch_bounds__(256) void sage_fused(
    const unsigned short* __restrict__ h, const unsigned short* __restrict__ Wcat,
    const float* __restrict__ bl, const float* __restrict__ br,
    const int* __restrict__ row_ptr, const int* __restrict__ csr,
    unsigned short* __restrict__ hOut) {
    __shared__ unsigned short aggs[64][136];   // 272B row stride: uniform banks
    __shared__ float ssh[2][64];
    const int tid = threadIdx.x;
    const int l = tid & 63;
    const int w = tid >> 6;
    const int g = l >> 4, c = l & 15;
    const int n0 = blockIdx.x * 64;

    // ---- phase 1: gather-mean into LDS ----
    for (int i = 0; i < 16; ++i) {
        int n_local = w * 16 + i;
        int n = n0 + n_local;
        int nd = n < NN ? n : NN - 1;
        int s0 = row_ptr[nd], s1 = row_ptr[nd + 1];
        if (n >= NN) s1 = s0;
        int len = s1 - s0;
        float inv = 1.0f / (float)(len > 0 ? len : 1);
        float acc[8];
#pragma unroll
        for (int q = 0; q < 8; ++q) acc[q] = 0.f;
        int j = s0 + g;
        // 4 independent row loads in flight per group
        for (; j + 12 < s1; j += 16) {
            int i0 = csr[j], i1 = csr[j + 4], i2 = csr[j + 8], i3 = csr[j + 12];
            bf16x8 v0 = *(const bf16x8*)(h + (size_t)i0 * DD + c * 8);
            bf16x8 v1 = *(const bf16x8*)(h + (size_t)i1 * DD + c * 8);
            bf16x8 v2 = *(const bf16x8*)(h + (size_t)i2 * DD + c * 8);
            bf16x8 v3 = *(const bf16x8*)(h + (size_t)i3 * DD + c * 8);
#pragma unroll
            for (int q = 0; q < 8; ++q)
                acc[q] += (bf2f((unsigned short)v0[q]) + bf2f((unsigned short)v1[q]))
                        + (bf2f((unsigned short)v2[q]) + bf2f((unsigned short)v3[q]));
        }
        for (; j < s1; j += 4) {
            int i0 = csr[j];
            bf16x8 v0 = *(const bf16x8*)(h + (size_t)i0 * DD + c * 8);
#pragma unroll
            for (int q = 0; q < 8; ++q) acc[q] += bf2f((unsigned short)v0[q]);
        }
#pragma unroll
        for (int q = 0; q < 8; ++q) {
            acc[q] += __shfl_xor(acc[q], 16);
            acc[q] += __shfl_xor(acc[q], 32);
        }
        if (g == 0) {
            bf16x8 r;
#pragma unroll
            for (int q = 0; q < 8; ++q) r[q] = (short)f2bf(acc[q] * inv);
            *(bf16x8*)(&aggs[n_local][c * 8]) = r;
        }
    }
    __syncthreads();

    // ---- phase 2: MFMA ----
    const int wm = w & 1, wn = w >> 1;
    const int l15 = l & 15, lg = l >> 4;

    f32x4 acc[2][4];
#pragma unroll
    for (int m = 0; m < 2; ++m)
#pragma unroll
        for (int n = 0; n < 4; ++n) acc[m][n] = (f32x4){0.f, 0.f, 0.f, 0.f};

    int nodeA[2];
#pragma unroll
    for (int m = 0; m < 2; ++m) {
        int r = n0 + wm * 32 + m * 16 + l15;
        nodeA[m] = r < NN ? r : NN - 1;
    }

#pragma unroll
    for (int ks = 0; ks < 8; ++ks) {
        const int kk = (ks & 3) * 32 + lg * 8;
        const int kw = ks * 32 + lg * 8;
        bf16x8 a[2], b[4];
        if (ks < 4) {
#pragma unroll
            for (int m = 0; m < 2; ++m)
                a[m] = *(const bf16x8*)(h + (size_t)nodeA[m] * DD + kk);
        } else {
#pragma unroll
            for (int m = 0; m < 2; ++m) {
                int row_local = wm * 32 + m * 16 + l15;
                a[m] = *(const bf16x8*)(&aggs[row_local][kk]);
            }
        }
#pragma unroll
        for (int n = 0; n < 4; ++n) {
            int o = wn * 64 + n * 16 + l15;
            b[n] = *(const bf16x8*)(Wcat + o * 256 + kw);
        }
#pragma unroll
        for (int m = 0; m < 2; ++m)
#pragma unroll
            for (int n = 0; n < 4; ++n)
                acc[m][n] = __builtin_amdgcn_mfma_f32_16x16x32_bf16(a[m], b[n], acc[m][n], 0, 0, 0);
    }

    float blv[4], brv[4];
#pragma unroll
    for (int n = 0; n < 4; ++n) {
        int o = wn * 64 + n * 16 + l15;
        blv[n] = bl[o]; brv[n] = br[o];
    }

    float outv[2][4][4];
#pragma unroll
    for (int m = 0; m < 2; ++m) {
#pragma unroll
        for (int r = 0; r < 4; ++r) {
            int row_local = wm * 32 + m * 16 + lg * 4 + r;
            int node = n0 + row_local;
            int nd = node < NN ? node : 0;
            float bf = (row_ptr[nd + 1] - row_ptr[nd]) > 0 ? 1.f : 0.f;
            float s = 0.f;
#pragma unroll
            for (int n = 0; n < 4; ++n) {
                float v = acc[m][n][r] + blv[n] + bf * brv[n];
                outv[m][n][r] = v;
                s = fmaf(v, v, s);
            }
            s += __shfl_xor(s, 1); s += __shfl_xor(s, 2);
            s += __shfl_xor(s, 4); s += __shfl_xor(s, 8);
            if (l15 == 0) ssh[wn][row_local] = s;
        }
    }
    __syncthreads();
#pragma unroll
    for (int m = 0; m < 2; ++m) {
#pragma unroll
        for (int r = 0; r < 4; ++r) {
            int row_local = wm * 32 + m * 16 + lg * 4 + r;
            int node = n0 + row_local;
            float tot = ssh[0][row_local] + ssh[1][row_local];
            float inv = 1.0f / fmaxf(sqrtf(tot), 1e-12f);
            if (node < NN) {
#pragma unroll
                for (int n = 0; n < 4; ++n) {
                    int o = wn * 64 + n * 16 + l15;
                    float v = fmaxf(outv[m][n][r], 0.f) * inv;
                    hOut[(size_t)node * DD + o] = f2bf(v);
                }
            }
        }
    }
}

// ---------------------------------------------------------------------------
// Pool: segment-mean of h3 (bf16) by sorted batch -> pooled[64][128], cnt[64]
// ---------------------------------------------------------------------------
__global__ __launch_bounds__(256) void pool_bf16(
    const unsigned short* __restrict__ h, const int* __restrict__ batch,
    float* __restrict__ pooled, float* __restrict__ cnt) {
    int hw = (blockIdx.x * blockDim.x + threadIdx.x) >> 5;
    int lane = threadIdx.x & 31;
    int total_hw = (gridDim.x * blockDim.x) >> 5;
    int chunk = (NN + total_hw - 1) / total_hw;
    int nbeg = hw * chunk;
    int nend = nbeg + chunk; if (nend > NN) nend = NN;
    if (nbeg >= nend) return;
    float ax = 0.f, ay = 0.f, az = 0.f, aw = 0.f;
    int curg = clampi(batch[nbeg], NG);
    int run = 0;
    for (int n = nbeg; n < nend; ++n) {
        int g = clampi(batch[n], NG);
        if (g != curg) {
            atomicAdd(&pooled[curg * DD + lane * 4 + 0], ax);
            atomicAdd(&pooled[curg * DD + lane * 4 + 1], ay);
            atomicAdd(&pooled[curg * DD + lane * 4 + 2], az);
            atomicAdd(&pooled[curg * DD + lane * 4 + 3], aw);
            if (lane == 0) atomicAdd(&cnt[curg], (float)run);
            ax = ay = az = aw = 0.f; run = 0; curg = g;
        }
        const ushort4 v = *(const ushort4*)(h + (size_t)n * DD + lane * 4);
        ax += bf2f(v.x); ay += bf2f(v.y); az += bf2f(v.z); aw += bf2f(v.w);
        ++run;
    }
    atomicAdd(&pooled[curg * DD + lane * 4 + 0], ax);
    atomicAdd(&pooled[curg * DD + lane * 4 + 1], ay);
    atomicAdd(&pooled[curg * DD + lane * 4 + 2], az);
    atomicAdd(&pooled[curg * DD + lane * 4 + 3], aw);
    if (lane == 0) atomicAdd(&cnt[curg], (float)run);
}

// ---------------------------------------------------------------------------
// Fold MLP: Wc = W2 @ W1 (16x128), bc = W2 @ b1 + b2
// ---------------------------------------------------------------------------
__global__ void mlpfold_kernel(const float* __restrict__ W1, const float* __restrict__ b1,
                               const float* __restrict__ W2, const float* __restrict__ b2,
                               float* __restrict__ Wc, float* __restrict__ bc) {
    int t = blockIdx.x * 256 + threadIdx.x;
    if (t >= 16 * 128) return;
    int o = t >> 7, k = t & 127;
    float s = 0.f;
    for (int j = 0; j < 128; ++j) s = fmaf(W2[o * 128 + j], W1[j * 128 + k], s);
    Wc[o * 128 + k] = s;
    if (k == 0) {
        float sb = 0.f;
        for (int j = 0; j < 128; ++j) sb = fmaf(W2[o * 128 + j], b1[j], sb);
        bc[o] = sb + b2[o];
    }
}

// ---------------------------------------------------------------------------
// Final: mean -> micro GEMM [64][128]@[128][16] -> log_softmax -> d_out
// ---------------------------------------------------------------------------
__global__ void final_kernel(const float* __restrict__ pooled, const float* __restrict__ cnt,
                             const float* __restrict__ Wc, const float* __restrict__ bc,
                             float* __restrict__ out) {
    int t = threadIdx.x;
    int g = t >> 4, o = t & 15;
    float invc = 1.0f / fmaxf(cnt[g], 1.0f);
    float z = bc[o];
    for (int k = 0; k < 128; ++k) z = fmaf(pooled[g * DD + k] * invc, Wc[o * 128 + k], z);
    float m = z;
    m = fmaxf(m, __shfl_xor(m, 1)); m = fmaxf(m, __shfl_xor(m, 2));
    m = fmaxf(m, __shfl_xor(m, 4)); m = fmaxf(m, __shfl_xor(m, 8));
    float e = expf(z - m);
    float s = e;
    s += __shfl_xor(s, 1); s += __shfl_xor(s, 2);
    s += __shfl_xor(s, 4); s += __shfl_xor(s, 8);
    out[g * 16 + o] = z - m - logf(s);
}

__global__ void zero_out_kernel(float* __restrict__ out, int n) {
    int i = blockIdx.x * 256 + threadIdx.x;
    if (i < n) out[i] = 0.f;
}

// ---------------------------------------------------------------------------
extern "C" void kernel_launch(void* const* d_in, const int* in_sizes, int n_in,
                              void* d_out, int out_size, void* d_ws, size_t ws_size,
                              hipStream_t stream) {
    const float* x  = (const float*)d_in[0];
    const int*   ei = (const int*)d_in[1];
    const int* batch = (const int*)d_in[2];
    const float* Wl = (const float*)d_in[3];
    const float* bl = (const float*)d_in[4];
    const float* Wr = (const float*)d_in[5];
    const float* br = (const float*)d_in[6];
    const float* W1 = (const float*)d_in[7];
    const float* b1 = (const float*)d_in[8];
    const float* W2 = (const float*)d_in[9];
    const float* b2 = (const float*)d_in[10];
    float* out = (float*)d_out;

    const int* src = ei;          // edge_index[0]
    const int* dst = ei + NE;     // edge_index[1]

    char* ws = (char*)d_ws;
    size_t off = 0;
    auto alloc = [&](size_t bytes) -> void* {
        void* p = ws + off; off += (bytes + 255) & ~(size_t)255; return p;
    };
    unsigned short* xb   = (unsigned short*)alloc((size_t)NN * DD * 2);
    unsigned short* hA   = (unsigned short*)alloc((size_t)NN * DD * 2);
    unsigned short* hB   = (unsigned short*)alloc((size_t)NN * DD * 2);
    unsigned short* Wcat = (unsigned short*)alloc((size_t)3 * 128 * 256 * 2);
    int* row_ptr  = (int*)alloc((size_t)(NN + 1) * 4);
    int* csr      = (int*)alloc((size_t)NE * 4);
    uint2* stage  = (uint2*)alloc((size_t)NE * 8);
    int* bcnt     = (int*)alloc((size_t)NB * 4);
    int* bstart   = (int*)alloc((size_t)(NB + 1) * 4);
    int* gcur     = (int*)alloc((size_t)NB * 4);
    float* pooled = (float*)alloc(NG * DD * 4);
    float* cnt    = (float*)alloc(NG * 4);
    float* Wc     = (float*)alloc(16 * DD * 4);
    float* bc     = (float*)alloc(16 * 4);

    if (off > ws_size) {
        zero_out_kernel<<<(out_size + 255) / 256, 256, 0, stream>>>(out, out_size);
        return;
    }

    // conversions (independent of CSR)
    cvt_x_kernel<<<(NN * DD / 4 + 255) / 256, 256, 0, stream>>>(x, xb);
    cvt_w_kernel<<<(3 * 128 * 256 + 255) / 256, 256, 0, stream>>>(Wl, Wr, Wcat);

    // CSR build via bucket sort (dense writes)
    hipMemsetAsync(bcnt, 0, (size_t)NB * 4, stream);
    const int npb = (NE + 7999) / 8000;   // 200 partition/count blocks
    bcount_kernel<<<npb, 256, 0, stream>>>(dst, bcnt);
    bscan_kernel<<<1, 1024, 0, stream>>>(bcnt, bstart, gcur);
    bpart_kernel<<<npb, 256, 0, stream>>>(src, dst, gcur, stage);
    bfill_kernel<<<NB, 256, 0, stream>>>(stage, bstart, row_ptr, csr);

    // 3 fused SAGE layers (gather + MFMA in one kernel)
    const unsigned short* hin = xb;
    unsigned short* bufs[2] = {hA, hB};
    for (int l = 0; l < 3; ++l) {
        unsigned short* hout = bufs[l & 1];
        sage_fused<<<(NN + 63) / 64, 256, 0, stream>>>(
            hin, Wcat + (size_t)l * 128 * 256,
            bl + (size_t)l * 128, br + (size_t)l * 128, row_ptr, csr, hout);
        hin = hout;
    }

    // pooled mean + folded MLP + log_softmax
    hipMemsetAsync(pooled, 0, (size_t)NG * DD * 4, stream);
    hipMemsetAsync(cnt, 0, (size_t)NG * 4, stream);
    pool_bf16<<<256, 256, 0, stream>>>(hin, batch, pooled, cnt);
    mlpfold_kernel<<<8, 256, 0, stream>>>(W1, b1, W2, b2, Wc, bc);
    final_kernel<<<1, 1024, 0, stream>>>(pooled, cnt, Wc, bc, out);
}

// Round 6
// 468.078 us; speedup vs baseline: 1.1490x; 1.1490x over previous
//
#include <hip/hip_runtime.h>
#include <cstdint>
#include <cstddef>

#define NN 100000   // nodes
#define NE 1600000  // edges
#define DD 128      // feature dim
#define NG 64       // graphs
#define NB 782      // buckets of 128 nodes: 782*128 = 100096 >= NN

using bf16x8 = __attribute__((ext_vector_type(8))) short;
using f32x4  = __attribute__((ext_vector_type(4))) float;

__device__ __forceinline__ int clampi(int v, int hi) {
    v = v < 0 ? 0 : v;
    return v >= hi ? hi - 1 : v;
}
__device__ __forceinline__ unsigned short f2bf(float f) {
    unsigned int u = __float_as_uint(f);
    u += 0x7fffu + ((u >> 16) & 1u);   // RNE
    return (unsigned short)(u >> 16);
}
__device__ __forceinline__ float bf2f(unsigned short s) {
    return __uint_as_float(((unsigned int)s) << 16);
}

// ---------------------------------------------------------------------------
// CSR build via bucket sort (all dense writes — no line-amplified scatter)
// ---------------------------------------------------------------------------
__global__ __launch_bounds__(256) void bcount_kernel(
    const int* __restrict__ dst, int* __restrict__ bcnt) {
    __shared__ int lcnt[NB];
    for (int i = threadIdx.x; i < NB; i += 256) lcnt[i] = 0;
    __syncthreads();
    int e0 = blockIdx.x * 8000;
    int e1 = e0 + 8000; if (e1 > NE) e1 = NE;
    for (int e = e0 + threadIdx.x; e < e1; e += 256)
        atomicAdd(&lcnt[clampi(dst[e], NN) >> 7], 1);
    __syncthreads();
    for (int i = threadIdx.x; i < NB; i += 256)
        if (lcnt[i]) atomicAdd(&bcnt[i], lcnt[i]);
}

__global__ __launch_bounds__(1024) void bscan_kernel(
    const int* __restrict__ bcnt, int* __restrict__ bstart, int* __restrict__ gcur) {
    __shared__ int sh[1024];
    int t = threadIdx.x;
    int own = (t < NB) ? bcnt[t] : 0;
    sh[t] = own;
    __syncthreads();
    for (int d = 1; d < 1024; d <<= 1) {
        int v = (t >= d) ? sh[t - d] : 0;
        __syncthreads();
        sh[t] += v;
        __syncthreads();
    }
    if (t < NB) {
        int excl = sh[t] - own;
        bstart[t] = excl;
        gcur[t] = excl;
    }
    if (t == NB - 1) bstart[NB] = sh[t];
}

__global__ __launch_bounds__(256) void bpart_kernel(
    const int* __restrict__ src, const int* __restrict__ dst,
    int* __restrict__ gcur, uint2* __restrict__ stage) {
    __shared__ int lds[NB];
    for (int i = threadIdx.x; i < NB; i += 256) lds[i] = 0;
    __syncthreads();
    int e0 = blockIdx.x * 8000;
    int e1 = e0 + 8000; if (e1 > NE) e1 = NE;
    for (int e = e0 + threadIdx.x; e < e1; e += 256)
        atomicAdd(&lds[clampi(dst[e], NN) >> 7], 1);
    __syncthreads();
    for (int i = threadIdx.x; i < NB; i += 256) {
        int c = lds[i];
        if (c) lds[i] = atomicAdd(&gcur[i], c);
    }
    __syncthreads();
    for (int e = e0 + threadIdx.x; e < e1; e += 256) {
        int d = clampi(dst[e], NN);
        int pos = atomicAdd(&lds[d >> 7], 1);
        uint2 p; p.x = (unsigned)clampi(src[e], NN); p.y = (unsigned)d;
        stage[pos] = p;
    }
}

__global__ __launch_bounds__(256) void bfill_kernel(
    const uint2* __restrict__ stage, const int* __restrict__ bstart,
    int* __restrict__ row_ptr, int* __restrict__ csr) {
    __shared__ int scnt[128];
    __shared__ int scur[128];
    const int b = blockIdx.x;
    const int t = threadIdx.x;
    const int s0 = bstart[b], s1 = bstart[b + 1];
    const int n0 = b << 7;
    int nend = NN - n0; if (nend > 128) nend = 128;
    if (t < 128) scnt[t] = 0;
    __syncthreads();
    for (int i = s0 + t; i < s1; i += 256)
        atomicAdd(&scnt[stage[i].y & 127], 1);
    __syncthreads();
    int own = (t < 128) ? scnt[t] : 0;
    for (int d = 1; d < 128; d <<= 1) {
        int v = (t < 128 && t >= d) ? scnt[t - d] : 0;
        __syncthreads();
        if (t < 128) scnt[t] += v;
        __syncthreads();
    }
    if (t < 128) {
        int excl = scnt[t] - own;
        scur[t] = excl;
        if (t < nend) row_ptr[n0 + t] = s0 + excl;
    }
    if (b == NB - 1 && t == 0) row_ptr[NN] = NE;
    __syncthreads();
    for (int i = s0 + t; i < s1; i += 256) {
        uint2 p = stage[i];
        int slot = atomicAdd(&scur[p.y & 127], 1);
        csr[s0 + slot] = (int)p.x;
    }
}

// ---------------------------------------------------------------------------
// Convert kernels
// ---------------------------------------------------------------------------
__global__ void cvt_x_kernel(const float* __restrict__ x, unsigned short* __restrict__ xb) {
    int i = blockIdx.x * 256 + threadIdx.x;
    if (i >= NN * DD / 4) return;
    const float4 v = ((const float4*)x)[i];
    ushort4 r;
    r.x = f2bf(v.x); r.y = f2bf(v.y); r.z = f2bf(v.z); r.w = f2bf(v.w);
    ((ushort4*)xb)[i] = r;
}

__global__ void cvt_w_kernel(const float* __restrict__ Wl, const float* __restrict__ Wr,
                             unsigned short* __restrict__ Wcat) {
    int t = blockIdx.x * 256 + threadIdx.x;
    if (t >= 3 * 128 * 256) return;
    int l = t >> 15;
    int rem = t & 32767;
    int o = rem >> 8, k = rem & 255;
    float v = (k < 128) ? Wl[(size_t)l * 16384 + o * 128 + k]
                        : Wr[(size_t)l * 16384 + o * 128 + (k - 128)];
    Wcat[t] = f2bf(v);
}

// ---------------------------------------------------------------------------
// Pull aggregation (bf16): one wave per dst node; 4 lane-groups of 16;
// each group keeps 4 independent row loads in flight (deg~16 => 1 iter).
// ---------------------------------------------------------------------------
__global__ __launch_bounds__(256) void pull16_kernel(
    const unsigned short* __restrict__ h, const int* __restrict__ row_ptr,
    const int* __restrict__ csr, unsigned short* __restrict__ agg) {
    int w = threadIdx.x >> 6, lane = threadIdx.x & 63;
    int n = blockIdx.x * 4 + w;
    if (n >= NN) return;
    int g = lane >> 4, c = lane & 15;
    int s0 = row_ptr[n], s1 = row_ptr[n + 1];
    int len = s1 - s0;
    float inv = 1.0f / (float)(len > 0 ? len : 1);
    float acc[8];
#pragma unroll
    for (int q = 0; q < 8; ++q) acc[q] = 0.f;
    int j = s0 + g;
    for (; j + 12 < s1; j += 16) {
        int i0 = csr[j], i1 = csr[j + 4], i2 = csr[j + 8], i3 = csr[j + 12];
        bf16x8 v0 = *(const bf16x8*)(h + (size_t)i0 * DD + c * 8);
        bf16x8 v1 = *(const bf16x8*)(h + (size_t)i1 * DD + c * 8);
        bf16x8 v2 = *(const bf16x8*)(h + (size_t)i2 * DD + c * 8);
        bf16x8 v3 = *(const bf16x8*)(h + (size_t)i3 * DD + c * 8);
#pragma unroll
        for (int q = 0; q < 8; ++q)
            acc[q] += (bf2f((unsigned short)v0[q]) + bf2f((unsigned short)v1[q]))
                    + (bf2f((unsigned short)v2[q]) + bf2f((unsigned short)v3[q]));
    }
    for (; j < s1; j += 4) {
        int i0 = csr[j];
        bf16x8 v0 = *(const bf16x8*)(h + (size_t)i0 * DD + c * 8);
#pragma unroll
        for (int q = 0; q < 8; ++q) acc[q] += bf2f((unsigned short)v0[q]);
    }
#pragma unroll
    for (int q = 0; q < 8; ++q) {
        acc[q] += __shfl_xor(acc[q], 16);
        acc[q] += __shfl_xor(acc[q], 32);
    }
    if (g == 0) {
        bf16x8 r;
#pragma unroll
        for (int q = 0; q < 8; ++q) r[q] = (short)f2bf(acc[q] * inv);
        *(bf16x8*)(agg + (size_t)n * DD + c * 8) = r;
    }
}

// ---------------------------------------------------------------------------
// Fused SAGE layer (MFMA bf16):
// out = relu(normalize(h@Wl^T + agg@Wr^T + bl + [deg>0]*br)) -> bf16
// ---------------------------------------------------------------------------
__global__ __launch_bounds__(256) void sage_mfma(
    const unsigned short* __restrict__ h, const unsigned short* __restrict__ agg,
    const unsigned short* __restrict__ Wcat, const float* __restrict__ bl,
    const float* __restrict__ br, const int* __restrict__ row_ptr,
    unsigned short* __restrict__ hOut) {
    __shared__ float ssh[2][64];
    const int tid = threadIdx.x;
    const int l = tid & 63;
    const int w = tid >> 6;
    const int wm = w & 1, wn = w >> 1;
    const int l15 = l & 15, lg = l >> 4;
    const int n0 = blockIdx.x * 64;

    f32x4 acc[2][4];
#pragma unroll
    for (int m = 0; m < 2; ++m)
#pragma unroll
        for (int n = 0; n < 4; ++n) acc[m][n] = (f32x4){0.f, 0.f, 0.f, 0.f};

    int nodeA[2];
#pragma unroll
    for (int m = 0; m < 2; ++m) {
        int r = n0 + wm * 32 + m * 16 + l15;
        nodeA[m] = r < NN ? r : NN - 1;
    }

#pragma unroll
    for (int ks = 0; ks < 8; ++ks) {
        const unsigned short* Abase = (ks < 4) ? h : agg;
        const int kk = (ks & 3) * 32 + lg * 8;
        const int kw = ks * 32 + lg * 8;
        bf16x8 a[2], b[4];
#pragma unroll
        for (int m = 0; m < 2; ++m)
            a[m] = *(const bf16x8*)(Abase + (size_t)nodeA[m] * DD + kk);
#pragma unroll
        for (int n = 0; n < 4; ++n) {
            int o = wn * 64 + n * 16 + l15;
            b[n] = *(const bf16x8*)(Wcat + o * 256 + kw);
        }
#pragma unroll
        for (int m = 0; m < 2; ++m)
#pragma unroll
            for (int n = 0; n < 4; ++n)
                acc[m][n] = __builtin_amdgcn_mfma_f32_16x16x32_bf16(a[m], b[n], acc[m][n], 0, 0, 0);
    }

    float blv[4], brv[4];
#pragma unroll
    for (int n = 0; n < 4; ++n) {
        int o = wn * 64 + n * 16 + l15;
        blv[n] = bl[o]; brv[n] = br[o];
    }

    float outv[2][4][4];
#pragma unroll
    for (int m = 0; m < 2; ++m) {
#pragma unroll
        for (int r = 0; r < 4; ++r) {
            int row_local = wm * 32 + m * 16 + lg * 4 + r;
            int node = n0 + row_local;
            int nd = node < NN ? node : 0;
            float bf = (row_ptr[nd + 1] - row_ptr[nd]) > 0 ? 1.f : 0.f;
            float s = 0.f;
#pragma unroll
            for (int n = 0; n < 4; ++n) {
                float v = acc[m][n][r] + blv[n] + bf * brv[n];
                outv[m][n][r] = v;
                s = fmaf(v, v, s);
            }
            s += __shfl_xor(s, 1); s += __shfl_xor(s, 2);
            s += __shfl_xor(s, 4); s += __shfl_xor(s, 8);
            if (l15 == 0) ssh[wn][row_local] = s;
        }
    }
    __syncthreads();
#pragma unroll
    for (int m = 0; m < 2; ++m) {
#pragma unroll
        for (int r = 0; r < 4; ++r) {
            int row_local = wm * 32 + m * 16 + lg * 4 + r;
            int node = n0 + row_local;
            float tot = ssh[0][row_local] + ssh[1][row_local];
            float inv = 1.0f / fmaxf(sqrtf(tot), 1e-12f);
            if (node < NN) {
#pragma unroll
                for (int n = 0; n < 4; ++n) {
                    int o = wn * 64 + n * 16 + l15;
                    float v = fmaxf(outv[m][n][r], 0.f) * inv;
                    hOut[(size_t)node * DD + o] = f2bf(v);
                }
            }
        }
    }
}

// ---------------------------------------------------------------------------
// Pool: segment-mean of h3 (bf16) by sorted batch -> pooled[64][128], cnt[64]
// ---------------------------------------------------------------------------
__global__ __launch_bounds__(256) void pool_bf16(
    const unsigned short* __restrict__ h, const int* __restrict__ batch,
    float* __restrict__ pooled, float* __restrict__ cnt) {
    int hw = (blockIdx.x * blockDim.x + threadIdx.x) >> 5;
    int lane = threadIdx.x & 31;
    int total_hw = (gridDim.x * blockDim.x) >> 5;
    int chunk = (NN + total_hw - 1) / total_hw;
    int nbeg = hw * chunk;
    int nend = nbeg + chunk; if (nend > NN) nend = NN;
    if (nbeg >= nend) return;
    float ax = 0.f, ay = 0.f, az = 0.f, aw = 0.f;
    int curg = clampi(batch[nbeg], NG);
    int run = 0;
    for (int n = nbeg; n < nend; ++n) {
        int g = clampi(batch[n], NG);
        if (g != curg) {
            atomicAdd(&pooled[curg * DD + lane * 4 + 0], ax);
            atomicAdd(&pooled[curg * DD + lane * 4 + 1], ay);
            atomicAdd(&pooled[curg * DD + lane * 4 + 2], az);
            atomicAdd(&pooled[curg * DD + lane * 4 + 3], aw);
            if (lane == 0) atomicAdd(&cnt[curg], (float)run);
            ax = ay = az = aw = 0.f; run = 0; curg = g;
        }
        const ushort4 v = *(const ushort4*)(h + (size_t)n * DD + lane * 4);
        ax += bf2f(v.x); ay += bf2f(v.y); az += bf2f(v.z); aw += bf2f(v.w);
        ++run;
    }
    atomicAdd(&pooled[curg * DD + lane * 4 + 0], ax);
    atomicAdd(&pooled[curg * DD + lane * 4 + 1], ay);
    atomicAdd(&pooled[curg * DD + lane * 4 + 2], az);
    atomicAdd(&pooled[curg * DD + lane * 4 + 3], aw);
    if (lane == 0) atomicAdd(&cnt[curg], (float)run);
}

// ---------------------------------------------------------------------------
// Fold MLP: Wc = W2 @ W1 (16x128), bc = W2 @ b1 + b2
// ---------------------------------------------------------------------------
__global__ void mlpfold_kernel(const float* __restrict__ W1, const float* __restrict__ b1,
                               const float* __restrict__ W2, const float* __restrict__ b2,
                               float* __restrict__ Wc, float* __restrict__ bc) {
    int t = blockIdx.x * 256 + threadIdx.x;
    if (t >= 16 * 128) return;
    int o = t >> 7, k = t & 127;
    float s = 0.f;
    for (int j = 0; j < 128; ++j) s = fmaf(W2[o * 128 + j], W1[j * 128 + k], s);
    Wc[o * 128 + k] = s;
    if (k == 0) {
        float sb = 0.f;
        for (int j = 0; j < 128; ++j) sb = fmaf(W2[o * 128 + j], b1[j], sb);
        bc[o] = sb + b2[o];
    }
}

// ---------------------------------------------------------------------------
// Final: mean -> micro GEMM [64][128]@[128][16] -> log_softmax -> d_out
// ---------------------------------------------------------------------------
__global__ void final_kernel(const float* __restrict__ pooled, const float* __restrict__ cnt,
                             const float* __restrict__ Wc, const float* __restrict__ bc,
                             float* __restrict__ out) {
    int t = threadIdx.x;
    int g = t >> 4, o = t & 15;
    float invc = 1.0f / fmaxf(cnt[g], 1.0f);
    float z = bc[o];
    for (int k = 0; k < 128; ++k) z = fmaf(pooled[g * DD + k] * invc, Wc[o * 128 + k], z);
    float m = z;
    m = fmaxf(m, __shfl_xor(m, 1)); m = fmaxf(m, __shfl_xor(m, 2));
    m = fmaxf(m, __shfl_xor(m, 4)); m = fmaxf(m, __shfl_xor(m, 8));
    float e = expf(z - m);
    float s = e;
    s += __shfl_xor(s, 1); s += __shfl_xor(s, 2);
    s += __shfl_xor(s, 4); s += __shfl_xor(s, 8);
    out[g * 16 + o] = z - m - logf(s);
}

__global__ void zero_out_kernel(float* __restrict__ out, int n) {
    int i = blockIdx.x * 256 + threadIdx.x;
    if (i < n) out[i] = 0.f;
}

// ---------------------------------------------------------------------------
extern "C" void kernel_launch(void* const* d_in, const int* in_sizes, int n_in,
                              void* d_out, int out_size, void* d_ws, size_t ws_size,
                              hipStream_t stream) {
    const float* x  = (const float*)d_in[0];
    const int*   ei = (const int*)d_in[1];
    const int* batch = (const int*)d_in[2];
    const float* Wl = (const float*)d_in[3];
    const float* bl = (const float*)d_in[4];
    const float* Wr = (const float*)d_in[5];
    const float* br = (const float*)d_in[6];
    const float* W1 = (const float*)d_in[7];
    const float* b1 = (const float*)d_in[8];
    const float* W2 = (const float*)d_in[9];
    const float* b2 = (const float*)d_in[10];
    float* out = (float*)d_out;

    const int* src = ei;          // edge_index[0]
    const int* dst = ei + NE;     // edge_index[1]

    char* ws = (char*)d_ws;
    size_t off = 0;
    auto alloc = [&](size_t bytes) -> void* {
        void* p = ws + off; off += (bytes + 255) & ~(size_t)255; return p;
    };
    unsigned short* xb   = (unsigned short*)alloc((size_t)NN * DD * 2);
    unsigned short* hA   = (unsigned short*)alloc((size_t)NN * DD * 2);
    unsigned short* hB   = (unsigned short*)alloc((size_t)NN * DD * 2);
    unsigned short* aggb = (unsigned short*)alloc((size_t)NN * DD * 2);
    unsigned short* Wcat = (unsigned short*)alloc((size_t)3 * 128 * 256 * 2);
    int* row_ptr  = (int*)alloc((size_t)(NN + 1) * 4);
    int* csr      = (int*)alloc((size_t)NE * 4);
    uint2* stage  = (uint2*)alloc((size_t)NE * 8);
    int* bcnt     = (int*)alloc((size_t)NB * 4);
    int* bstart   = (int*)alloc((size_t)(NB + 1) * 4);
    int* gcur     = (int*)alloc((size_t)NB * 4);
    float* pooled = (float*)alloc(NG * DD * 4);
    float* cnt    = (float*)alloc(NG * 4);
    float* Wc     = (float*)alloc(16 * DD * 4);
    float* bc     = (float*)alloc(16 * 4);

    if (off > ws_size) {
        zero_out_kernel<<<(out_size + 255) / 256, 256, 0, stream>>>(out, out_size);
        return;
    }

    // conversions (independent of CSR)
    cvt_x_kernel<<<(NN * DD / 4 + 255) / 256, 256, 0, stream>>>(x, xb);
    cvt_w_kernel<<<(3 * 128 * 256 + 255) / 256, 256, 0, stream>>>(Wl, Wr, Wcat);

    // CSR build via bucket sort (dense writes)
    hipMemsetAsync(bcnt, 0, (size_t)NB * 4, stream);
    const int npb = (NE + 7999) / 8000;   // 200 partition/count blocks
    bcount_kernel<<<npb, 256, 0, stream>>>(dst, bcnt);
    bscan_kernel<<<1, 1024, 0, stream>>>(bcnt, bstart, gcur);
    bpart_kernel<<<npb, 256, 0, stream>>>(src, dst, gcur, stage);
    bfill_kernel<<<NB, 256, 0, stream>>>(stage, bstart, row_ptr, csr);

    // 3 SAGE layers (split: latency-bound pull at full occupancy, then MFMA)
    const unsigned short* hin = xb;
    unsigned short* bufs[2] = {hA, hB};
    for (int l = 0; l < 3; ++l) {
        unsigned short* hout = bufs[l & 1];
        pull16_kernel<<<(NN + 3) / 4, 256, 0, stream>>>(hin, row_ptr, csr, aggb);
        sage_mfma<<<(NN + 63) / 64, 256, 0, stream>>>(
            hin, aggb, Wcat + (size_t)l * 128 * 256,
            bl + (size_t)l * 128, br + (size_t)l * 128, row_ptr, hout);
        hin = hout;
    }

    // pooled mean + folded MLP + log_softmax
    hipMemsetAsync(pooled, 0, (size_t)NG * DD * 4, stream);
    hipMemsetAsync(cnt, 0, (size_t)NG * 4, stream);
    pool_bf16<<<256, 256, 0, stream>>>(hin, batch, pooled, cnt);
    mlpfold_kernel<<<8, 256, 0, stream>>>(W1, b1, W2, b2, Wc, bc);
    final_kernel<<<1, 1024, 0, stream>>>(pooled, cnt, Wc, bc, out);
}

// Round 7
// 458.012 us; speedup vs baseline: 1.1742x; 1.0220x over previous
//
#include <hip/hip_runtime.h>
#include <cstdint>
#include <cstddef>

#define NN 100000   // nodes
#define NE 1600000  // edges
#define DD 128      // feature dim
#define NG 64       // graphs
#define NB 782      // buckets of 128 nodes: 782*128 = 100096 >= NN
#define NTILE 1563  // ceil(NN/64)
#define SGRID 782   // sage grid: 2 tiles per block

using bf16x8 = __attribute__((ext_vector_type(8))) short;
using f32x4  = __attribute__((ext_vector_type(4))) float;

__device__ __forceinline__ int clampi(int v, int hi) {
    v = v < 0 ? 0 : v;
    return v >= hi ? hi - 1 : v;
}
__device__ __forceinline__ unsigned short f2bf(float f) {
    unsigned int u = __float_as_uint(f);
    u += 0x7fffu + ((u >> 16) & 1u);   // RNE
    return (unsigned short)(u >> 16);
}
__device__ __forceinline__ float bf2f(unsigned short s) {
    return __uint_as_float(((unsigned int)s) << 16);
}

// ---------------------------------------------------------------------------
// CSR build via bucket sort (all dense writes — no line-amplified scatter)
// ---------------------------------------------------------------------------
__global__ __launch_bounds__(256) void bcount_kernel(
    const int* __restrict__ dst, int* __restrict__ bcnt) {
    __shared__ int lcnt[NB];
    for (int i = threadIdx.x; i < NB; i += 256) lcnt[i] = 0;
    __syncthreads();
    int e0 = blockIdx.x * 8000;
    int e1 = e0 + 8000; if (e1 > NE) e1 = NE;
    for (int e = e0 + threadIdx.x; e < e1; e += 256)
        atomicAdd(&lcnt[clampi(dst[e], NN) >> 7], 1);
    __syncthreads();
    for (int i = threadIdx.x; i < NB; i += 256)
        if (lcnt[i]) atomicAdd(&bcnt[i], lcnt[i]);
}

__global__ __launch_bounds__(1024) void bscan_kernel(
    const int* __restrict__ bcnt, int* __restrict__ bstart, int* __restrict__ gcur) {
    __shared__ int sh[1024];
    int t = threadIdx.x;
    int own = (t < NB) ? bcnt[t] : 0;
    sh[t] = own;
    __syncthreads();
    for (int d = 1; d < 1024; d <<= 1) {
        int v = (t >= d) ? sh[t - d] : 0;
        __syncthreads();
        sh[t] += v;
        __syncthreads();
    }
    if (t < NB) {
        int excl = sh[t] - own;
        bstart[t] = excl;
        gcur[t] = excl;
    }
    if (t == NB - 1) bstart[NB] = sh[t];
}

__global__ __launch_bounds__(256) void bpart_kernel(
    const int* __restrict__ src, const int* __restrict__ dst,
    int* __restrict__ gcur, uint2* __restrict__ stage) {
    __shared__ int lds[NB];
    for (int i = threadIdx.x; i < NB; i += 256) lds[i] = 0;
    __syncthreads();
    int e0 = blockIdx.x * 8000;
    int e1 = e0 + 8000; if (e1 > NE) e1 = NE;
    for (int e = e0 + threadIdx.x; e < e1; e += 256)
        atomicAdd(&lds[clampi(dst[e], NN) >> 7], 1);
    __syncthreads();
    for (int i = threadIdx.x; i < NB; i += 256) {
        int c = lds[i];
        if (c) lds[i] = atomicAdd(&gcur[i], c);
    }
    __syncthreads();
    for (int e = e0 + threadIdx.x; e < e1; e += 256) {
        int d = clampi(dst[e], NN);
        int pos = atomicAdd(&lds[d >> 7], 1);
        uint2 p; p.x = (unsigned)clampi(src[e], NN); p.y = (unsigned)d;
        stage[pos] = p;
    }
}

__global__ __launch_bounds__(256) void bfill_kernel(
    const uint2* __restrict__ stage, const int* __restrict__ bstart,
    int* __restrict__ row_ptr, int* __restrict__ csr) {
    __shared__ int scnt[128];
    __shared__ int scur[128];
    const int b = blockIdx.x;
    const int t = threadIdx.x;
    const int s0 = bstart[b], s1 = bstart[b + 1];
    const int n0 = b << 7;
    int nend = NN - n0; if (nend > 128) nend = 128;
    if (t < 128) scnt[t] = 0;
    __syncthreads();
    for (int i = s0 + t; i < s1; i += 256)
        atomicAdd(&scnt[stage[i].y & 127], 1);
    __syncthreads();
    int own = (t < 128) ? scnt[t] : 0;
    for (int d = 1; d < 128; d <<= 1) {
        int v = (t < 128 && t >= d) ? scnt[t - d] : 0;
        __syncthreads();
        if (t < 128) scnt[t] += v;
        __syncthreads();
    }
    if (t < 128) {
        int excl = scnt[t] - own;
        scur[t] = excl;
        if (t < nend) row_ptr[n0 + t] = s0 + excl;
    }
    if (b == NB - 1 && t == 0) row_ptr[NN] = NE;
    __syncthreads();
    for (int i = s0 + t; i < s1; i += 256) {
        uint2 p = stage[i];
        int slot = atomicAdd(&scur[p.y & 127], 1);
        csr[s0 + slot] = (int)p.x;
    }
}

// ---------------------------------------------------------------------------
// Fused convert: x f32 -> bf16, and weights -> concatenated bf16 [l][o][256]
// ---------------------------------------------------------------------------
#define XQ (NN * DD / 4)          // 3,200,000 float4 groups
#define WTOT (3 * 128 * 256)      // 98,304 weight elements
__global__ void cvt_kernel(const float* __restrict__ x,
                           const float* __restrict__ Wl, const float* __restrict__ Wr,
                           unsigned short* __restrict__ xb,
                           unsigned short* __restrict__ Wcat) {
    int i = blockIdx.x * 256 + threadIdx.x;
    if (i < XQ) {
        const float4 v = ((const float4*)x)[i];
        ushort4 r;
        r.x = f2bf(v.x); r.y = f2bf(v.y); r.z = f2bf(v.z); r.w = f2bf(v.w);
        ((ushort4*)xb)[i] = r;
    } else {
        int t = i - XQ;
        if (t < WTOT) {
            int l = t >> 15;
            int rem = t & 32767;
            int o = rem >> 8, k = rem & 255;
            float v = (k < 128) ? Wl[(size_t)l * 16384 + o * 128 + k]
                                : Wr[(size_t)l * 16384 + o * 128 + (k - 128)];
            Wcat[t] = f2bf(v);
        }
    }
}

// ---------------------------------------------------------------------------
// Pull aggregation (bf16): one wave per dst node; 4 lane-groups of 16;
// each group keeps 4 independent row loads in flight.
// ---------------------------------------------------------------------------
__global__ __launch_bounds__(256) void pull16_kernel(
    const unsigned short* __restrict__ h, const int* __restrict__ row_ptr,
    const int* __restrict__ csr, unsigned short* __restrict__ agg) {
    int w = threadIdx.x >> 6, lane = threadIdx.x & 63;
    int n = blockIdx.x * 4 + w;
    if (n >= NN) return;
    int g = lane >> 4, c = lane & 15;
    int s0 = row_ptr[n], s1 = row_ptr[n + 1];
    int len = s1 - s0;
    float inv = 1.0f / (float)(len > 0 ? len : 1);
    float acc[8];
#pragma unroll
    for (int q = 0; q < 8; ++q) acc[q] = 0.f;
    int j = s0 + g;
    for (; j + 12 < s1; j += 16) {
        int i0 = csr[j], i1 = csr[j + 4], i2 = csr[j + 8], i3 = csr[j + 12];
        bf16x8 v0 = *(const bf16x8*)(h + (size_t)i0 * DD + c * 8);
        bf16x8 v1 = *(const bf16x8*)(h + (size_t)i1 * DD + c * 8);
        bf16x8 v2 = *(const bf16x8*)(h + (size_t)i2 * DD + c * 8);
        bf16x8 v3 = *(const bf16x8*)(h + (size_t)i3 * DD + c * 8);
#pragma unroll
        for (int q = 0; q < 8; ++q)
            acc[q] += (bf2f((unsigned short)v0[q]) + bf2f((unsigned short)v1[q]))
                    + (bf2f((unsigned short)v2[q]) + bf2f((unsigned short)v3[q]));
    }
    for (; j < s1; j += 4) {
        int i0 = csr[j];
        bf16x8 v0 = *(const bf16x8*)(h + (size_t)i0 * DD + c * 8);
#pragma unroll
        for (int q = 0; q < 8; ++q) acc[q] += bf2f((unsigned short)v0[q]);
    }
#pragma unroll
    for (int q = 0; q < 8; ++q) {
        acc[q] += __shfl_xor(acc[q], 16);
        acc[q] += __shfl_xor(acc[q], 32);
    }
    if (g == 0) {
        bf16x8 r;
#pragma unroll
        for (int q = 0; q < 8; ++q) r[q] = (short)f2bf(acc[q] * inv);
        *(bf16x8*)(agg + (size_t)n * DD + c * 8) = r;
    }
}

// ---------------------------------------------------------------------------
// SAGE layer v2 (MFMA bf16, persistent B-registers, grid-stride over tiles):
// out = relu(normalize(h@Wl^T + agg@Wr^T + bl + [deg>0]*br)) -> bf16
// Each wave holds its 32 B fragments (128 VGPR) for the whole kernel;
// per tile: 16 upfront A loads, 64 register-only MFMAs.
// ---------------------------------------------------------------------------
__global__ __launch_bounds__(256) void sage_mfma2(
    const unsigned short* __restrict__ h, const unsigned short* __restrict__ agg,
    const unsigned short* __restrict__ Wcat, const float* __restrict__ bl,
    const float* __restrict__ br, const int* __restrict__ row_ptr,
    unsigned short* __restrict__ hOut) {
    __shared__ float ssh[2][64];
    const int tid = threadIdx.x;
    const int l = tid & 63;
    const int w = tid >> 6;
    const int wm = w & 1, wn = w >> 1;
    const int l15 = l & 15, lg = l >> 4;

    // persistent B fragments (reused across tiles)
    bf16x8 b[8][4];
#pragma unroll
    for (int ks = 0; ks < 8; ++ks)
#pragma unroll
        for (int n = 0; n < 4; ++n) {
            int o = wn * 64 + n * 16 + l15;
            b[ks][n] = *(const bf16x8*)(Wcat + o * 256 + ks * 32 + lg * 8);
        }

    float blv[4], brv[4];
#pragma unroll
    for (int n = 0; n < 4; ++n) {
        int o = wn * 64 + n * 16 + l15;
        blv[n] = bl[o]; brv[n] = br[o];
    }

    for (int t = blockIdx.x; t < NTILE; t += SGRID) {
        const int n0 = t * 64;
        int nodeA[2];
#pragma unroll
        for (int m = 0; m < 2; ++m) {
            int r = n0 + wm * 32 + m * 16 + l15;
            nodeA[m] = r < NN ? r : NN - 1;
        }

        // all 16 A fragments upfront (independent loads, deep in flight)
        bf16x8 a[8][2];
#pragma unroll
        for (int ks = 0; ks < 8; ++ks) {
            const unsigned short* Ab = (ks < 4) ? h : agg;
            const int kk = (ks & 3) * 32 + lg * 8;
#pragma unroll
            for (int m = 0; m < 2; ++m)
                a[ks][m] = *(const bf16x8*)(Ab + (size_t)nodeA[m] * DD + kk);
        }

        f32x4 acc[2][4];
#pragma unroll
        for (int m = 0; m < 2; ++m)
#pragma unroll
            for (int n = 0; n < 4; ++n) acc[m][n] = (f32x4){0.f, 0.f, 0.f, 0.f};

#pragma unroll
        for (int ks = 0; ks < 8; ++ks)
#pragma unroll
            for (int m = 0; m < 2; ++m)
#pragma unroll
                for (int n = 0; n < 4; ++n)
                    acc[m][n] = __builtin_amdgcn_mfma_f32_16x16x32_bf16(a[ks][m], b[ks][n], acc[m][n], 0, 0, 0);

        // epilogue: bias, cross-wave row L2-norm, relu, bf16 store (acc reused)
#pragma unroll
        for (int m = 0; m < 2; ++m) {
#pragma unroll
            for (int r = 0; r < 4; ++r) {
                int row_local = wm * 32 + m * 16 + lg * 4 + r;
                int node = n0 + row_local;
                int nd = node < NN ? node : 0;
                float bf = (row_ptr[nd + 1] - row_ptr[nd]) > 0 ? 1.f : 0.f;
                float s = 0.f;
#pragma unroll
                for (int n = 0; n < 4; ++n) {
                    float v = acc[m][n][r] + blv[n] + bf * brv[n];
                    acc[m][n][r] = v;
                    s = fmaf(v, v, s);
                }
                s += __shfl_xor(s, 1); s += __shfl_xor(s, 2);
                s += __shfl_xor(s, 4); s += __shfl_xor(s, 8);
                if (l15 == 0) ssh[wn][row_local] = s;
            }
        }
        __syncthreads();
#pragma unroll
        for (int m = 0; m < 2; ++m) {
#pragma unroll
            for (int r = 0; r < 4; ++r) {
                int row_local = wm * 32 + m * 16 + lg * 4 + r;
                int node = n0 + row_local;
                float tot = ssh[0][row_local] + ssh[1][row_local];
                float inv = 1.0f / fmaxf(sqrtf(tot), 1e-12f);
                if (node < NN) {
#pragma unroll
                    for (int n = 0; n < 4; ++n) {
                        int o = wn * 64 + n * 16 + l15;
                        float v = fmaxf(acc[m][n][r], 0.f) * inv;
                        hOut[(size_t)node * DD + o] = f2bf(v);
                    }
                }
            }
        }
        __syncthreads();   // ssh reuse hazard across tiles
    }
}

// ---------------------------------------------------------------------------
// Pool: segment-mean of h3 (bf16) by sorted batch -> pooled[64][128], cnt[64]
// ---------------------------------------------------------------------------
__global__ __launch_bounds__(256) void pool_bf16(
    const unsigned short* __restrict__ h, const int* __restrict__ batch,
    float* __restrict__ pooled, float* __restrict__ cnt) {
    int hw = (blockIdx.x * blockDim.x + threadIdx.x) >> 5;
    int lane = threadIdx.x & 31;
    int total_hw = (gridDim.x * blockDim.x) >> 5;
    int chunk = (NN + total_hw - 1) / total_hw;
    int nbeg = hw * chunk;
    int nend = nbeg + chunk; if (nend > NN) nend = NN;
    if (nbeg >= nend) return;
    float ax = 0.f, ay = 0.f, az = 0.f, aw = 0.f;
    int curg = clampi(batch[nbeg], NG);
    int run = 0;
    for (int n = nbeg; n < nend; ++n) {
        int g = clampi(batch[n], NG);
        if (g != curg) {
            atomicAdd(&pooled[curg * DD + lane * 4 + 0], ax);
            atomicAdd(&pooled[curg * DD + lane * 4 + 1], ay);
            atomicAdd(&pooled[curg * DD + lane * 4 + 2], az);
            atomicAdd(&pooled[curg * DD + lane * 4 + 3], aw);
            if (lane == 0) atomicAdd(&cnt[curg], (float)run);
            ax = ay = az = aw = 0.f; run = 0; curg = g;
        }
        const ushort4 v = *(const ushort4*)(h + (size_t)n * DD + lane * 4);
        ax += bf2f(v.x); ay += bf2f(v.y); az += bf2f(v.z); aw += bf2f(v.w);
        ++run;
    }
    atomicAdd(&pooled[curg * DD + lane * 4 + 0], ax);
    atomicAdd(&pooled[curg * DD + lane * 4 + 1], ay);
    atomicAdd(&pooled[curg * DD + lane * 4 + 2], az);
    atomicAdd(&pooled[curg * DD + lane * 4 + 3], aw);
    if (lane == 0) atomicAdd(&cnt[curg], (float)run);
}

// ---------------------------------------------------------------------------
// Fused tail: fold MLP (Wc = W2@W1 in LDS) + mean + micro-GEMM + log_softmax
// Single block, 1024 threads.
// ---------------------------------------------------------------------------
__global__ __launch_bounds__(1024) void tail_kernel(
    const float* __restrict__ pooled, const float* __restrict__ cnt,
    const float* __restrict__ W1, const float* __restrict__ b1,
    const float* __restrict__ W2, const float* __restrict__ b2,
    float* __restrict__ out) {
    __shared__ float Wc[16][128];
    __shared__ float bcs[16];
    int t = threadIdx.x;
    for (int i = t; i < 2048; i += 1024) {
        int o = i >> 7, k = i & 127;
        float s = 0.f;
        for (int j = 0; j < 128; ++j) s = fmaf(W2[o * 128 + j], W1[j * 128 + k], s);
        Wc[o][k] = s;
    }
    if (t < 16) {
        float sb = 0.f;
        for (int j = 0; j < 128; ++j) sb = fmaf(W2[t * 128 + j], b1[j], sb);
        bcs[t] = sb + b2[t];
    }
    __syncthreads();
    int g = t >> 4, o = t & 15;
    float invc = 1.0f / fmaxf(cnt[g], 1.0f);
    float z = bcs[o];
    for (int k = 0; k < 128; ++k) z = fmaf(pooled[g * DD + k] * invc, Wc[o][k], z);
    float m = z;
    m = fmaxf(m, __shfl_xor(m, 1)); m = fmaxf(m, __shfl_xor(m, 2));
    m = fmaxf(m, __shfl_xor(m, 4)); m = fmaxf(m, __shfl_xor(m, 8));
    float e = expf(z - m);
    float s = e;
    s += __shfl_xor(s, 1); s += __shfl_xor(s, 2);
    s += __shfl_xor(s, 4); s += __shfl_xor(s, 8);
    out[g * 16 + o] = z - m - logf(s);
}

__global__ void zero_out_kernel(float* __restrict__ out, int n) {
    int i = blockIdx.x * 256 + threadIdx.x;
    if (i < n) out[i] = 0.f;
}

// ---------------------------------------------------------------------------
extern "C" void kernel_launch(void* const* d_in, const int* in_sizes, int n_in,
                              void* d_out, int out_size, void* d_ws, size_t ws_size,
                              hipStream_t stream) {
    const float* x  = (const float*)d_in[0];
    const int*   ei = (const int*)d_in[1];
    const int* batch = (const int*)d_in[2];
    const float* Wl = (const float*)d_in[3];
    const float* bl = (const float*)d_in[4];
    const float* Wr = (const float*)d_in[5];
    const float* br = (const float*)d_in[6];
    const float* W1 = (const float*)d_in[7];
    const float* b1 = (const float*)d_in[8];
    const float* W2 = (const float*)d_in[9];
    const float* b2 = (const float*)d_in[10];
    float* out = (float*)d_out;

    const int* src = ei;          // edge_index[0]
    const int* dst = ei + NE;     // edge_index[1]

    char* ws = (char*)d_ws;
    size_t off = 0;
    auto alloc = [&](size_t bytes) -> void* {
        void* p = ws + off; off += (bytes + 255) & ~(size_t)255; return p;
    };
    unsigned short* xb   = (unsigned short*)alloc((size_t)NN * DD * 2);
    unsigned short* hA   = (unsigned short*)alloc((size_t)NN * DD * 2);
    unsigned short* hB   = (unsigned short*)alloc((size_t)NN * DD * 2);
    unsigned short* aggb = (unsigned short*)alloc((size_t)NN * DD * 2);
    unsigned short* Wcat = (unsigned short*)alloc((size_t)WTOT * 2);
    int* row_ptr  = (int*)alloc((size_t)(NN + 1) * 4);
    int* csr      = (int*)alloc((size_t)NE * 4);
    uint2* stage  = (uint2*)alloc((size_t)NE * 8);
    int* bcnt     = (int*)alloc((size_t)NB * 4);
    int* bstart   = (int*)alloc((size_t)(NB + 1) * 4);
    int* gcur     = (int*)alloc((size_t)NB * 4);
    float* pooled = (float*)alloc(NG * DD * 4);   // pooled+cnt adjacent:
    float* cnt    = (float*)alloc(NG * 4);        // single memset below

    if (off > ws_size) {
        zero_out_kernel<<<(out_size + 255) / 256, 256, 0, stream>>>(out, out_size);
        return;
    }

    // fused conversions
    cvt_kernel<<<(XQ + WTOT + 255) / 256, 256, 0, stream>>>(x, Wl, Wr, xb, Wcat);

    // CSR build via bucket sort (dense writes)
    hipMemsetAsync(bcnt, 0, (size_t)NB * 4, stream);
    const int npb = (NE + 7999) / 8000;   // 200 partition/count blocks
    bcount_kernel<<<npb, 256, 0, stream>>>(dst, bcnt);
    bscan_kernel<<<1, 1024, 0, stream>>>(bcnt, bstart, gcur);
    bpart_kernel<<<npb, 256, 0, stream>>>(src, dst, gcur, stage);
    bfill_kernel<<<NB, 256, 0, stream>>>(stage, bstart, row_ptr, csr);

    // 3 SAGE layers (split: latency-bound pull at full occupancy, then MFMA)
    const unsigned short* hin = xb;
    unsigned short* bufs[2] = {hA, hB};
    for (int l = 0; l < 3; ++l) {
        unsigned short* hout = bufs[l & 1];
        pull16_kernel<<<(NN + 3) / 4, 256, 0, stream>>>(hin, row_ptr, csr, aggb);
        sage_mfma2<<<SGRID, 256, 0, stream>>>(
            hin, aggb, Wcat + (size_t)l * 128 * 256,
            bl + (size_t)l * 128, br + (size_t)l * 128, row_ptr, hout);
        hin = hout;
    }

    // pooled mean + fused fold/final tail
    hipMemsetAsync(pooled, 0, (size_t)NG * DD * 4 + NG * 4, stream);
    pool_bf16<<<256, 256, 0, stream>>>(hin, batch, pooled, cnt);
    tail_kernel<<<1, 1024, 0, stream>>>(pooled, cnt, W1, b1, W2, b2, out);
}